// Round 15
// baseline (1774.589 us; speedup 1.0000x reference)
//
#include <hip/hip_runtime.h>
#include <hip/hip_bf16.h>
#include <hip/hip_fp16.h>

typedef _Float16 f16;
typedef _Float16 f16x8 __attribute__((ext_vector_type(8)));
typedef float f32x4 __attribute__((ext_vector_type(4)));
typedef unsigned int u32;
typedef unsigned short u16;
typedef unsigned long long u64;

#define HB 2048
#define DD 2048
#define TT 256
#define BB 64

typedef const __attribute__((address_space(1))) u32 gu32;
typedef __attribute__((address_space(3))) u32 lu32;

__device__ __forceinline__ void gl_lds16(const void* g, void* l) {
    __builtin_amdgcn_global_load_lds((gu32*)g, (lu32*)l, 16, 0, 0);
}

// 8x global_load_dwordx4, sc0: L1-bypass, served by L2 (dirty same-XCD) or L3 refill
#define LOADM_SC0(dst, ar)                                                    \
    asm volatile("global_load_dwordx4 %0, %8, off sc0\n\t"                    \
                 "global_load_dwordx4 %1, %8, off offset:64 sc0\n\t"          \
                 "global_load_dwordx4 %2, %8, off offset:128 sc0\n\t"         \
                 "global_load_dwordx4 %3, %8, off offset:192 sc0\n\t"         \
                 "global_load_dwordx4 %4, %8, off offset:256 sc0\n\t"         \
                 "global_load_dwordx4 %5, %8, off offset:320 sc0\n\t"         \
                 "global_load_dwordx4 %6, %8, off offset:384 sc0\n\t"         \
                 "global_load_dwordx4 %7, %8, off offset:448 sc0"             \
                 : "=&v"(dst[0]), "=&v"(dst[1]), "=&v"(dst[2]), "=&v"(dst[3]),\
                   "=&v"(dst[4]), "=&v"(dst[5]), "=&v"(dst[6]), "=&v"(dst[7]) \
                 : "v"(ar)                                                    \
                 : "memory")

#define VMCNT0 asm volatile("s_waitcnt vmcnt(0)" ::: "memory")
#define VMCNT4 asm volatile("s_waitcnt vmcnt(4)" ::: "memory")

__device__ __forceinline__ u32 ld_flag_sc0(const u32* p) {
    u32 v;
    asm volatile("global_load_dword %0, %1, off sc0\n\ts_waitcnt vmcnt(0)"
                 : "=v"(v) : "v"(p) : "memory");
    return v;
}
__device__ __forceinline__ u32 ld_flag_sc1(const u32* p) {
    u32 v;
    asm volatile("global_load_dword %0, %1, off sc1\n\ts_waitcnt vmcnt(0)"
                 : "=v"(v) : "v"(p) : "memory");
    return v;
}
__device__ __forceinline__ void st_u16_sc1(void* p, u16 v) {
    asm volatile("global_store_short %0, %1, off sc1" :: "v"(p), "v"(v) : "memory");
}

// ---------- transpose + convert fp32 [R][C] -> fp16 [C][R] (square 2048) ----------
__global__ __launch_bounds__(256) void k_transpose_cvt(const float* __restrict__ src,
                                                       f16* __restrict__ dst) {
    __shared__ f16 tile[64][65];
    int bx = blockIdx.x * 64;
    int by = blockIdx.y * 64;
    int tx = threadIdx.x & 63;
    int ty = threadIdx.x >> 6;
#pragma unroll
    for (int r = ty; r < 64; r += 4)
        tile[r][tx] = (f16)src[(size_t)(by + r) * HB + bx + tx];
    __syncthreads();
#pragma unroll
    for (int r = ty; r < 64; r += 4)
        dst[(size_t)(bx + r) * HB + by + tx] = tile[tx][r];
}

// ---------- convert/gather x [b][t][d] fp32 -> a16 [t*64+b][d] fp16 ----------
__global__ __launch_bounds__(256) void k_cvt_x(const float* __restrict__ x,
                                               f16* __restrict__ a16) {
    int r = blockIdx.x;  // r = t*64+b
    int d = threadIdx.x * 8;
    const float* src = x + ((size_t)(r & 63) * TT + (r >> 6)) * DD + d;
    float4 v0 = *(const float4*)src;
    float4 v1 = *(const float4*)(src + 4);
    f16x8 o = {(f16)v0.x, (f16)v0.y, (f16)v0.z, (f16)v0.w,
               (f16)v1.x, (f16)v1.y, (f16)v1.z, (f16)v1.w};
    *(f16x8*)(a16 + (size_t)r * DD + d) = o;
}

// ---------- phase 1: 128x128x32 LDS-staged MFMA GEMM, xw16 = a16 @ W + b ----------
__global__ __launch_bounds__(256) void k_gemm_xw_lds(const f16* __restrict__ a16,
                                                     const f16* __restrict__ W16T,
                                                     const float* __restrict__ bias,
                                                     f16* __restrict__ xw16) {
    __shared__ f16 As[128 * 32];
    __shared__ f16 Bs[128 * 32];
    int tid = threadIdx.x;
    int lane = tid & 63, w = tid >> 6;
    int wr = w >> 1, wc = w & 1;
    int lr = lane & 15, kg = lane >> 4;
    int rowBase = blockIdx.y * 128;
    int colBase = blockIdx.x * 128;

    f32x4 acc[4][4] = {};

    int r0 = tid >> 2, c0 = ((tid & 3) ^ ((r0 >> 1) & 3)) * 8;
    int u1 = tid + 256;
    int r1 = u1 >> 2, c1 = ((u1 & 3) ^ ((r1 >> 1) & 3)) * 8;
    const f16* gA0 = a16 + (size_t)(rowBase + r0) * DD + c0;
    const f16* gA1 = a16 + (size_t)(rowBase + r1) * DD + c1;
    const f16* gB0 = W16T + (size_t)(colBase + r0) * DD + c0;
    const f16* gB1 = W16T + (size_t)(colBase + r1) * DD + c1;
    f16* lA0 = As + (size_t)(w * 64) * 8;
    f16* lA1 = As + (size_t)(256 + w * 64) * 8;
    f16* lB0 = Bs + (size_t)(w * 64) * 8;
    f16* lB1 = Bs + (size_t)(256 + w * 64) * 8;

    for (int kk = 0; kk < DD; kk += 32) {
        gl_lds16(gA0 + kk, lA0);
        gl_lds16(gA1 + kk, lA1);
        gl_lds16(gB0 + kk, lB0);
        gl_lds16(gB1 + kk, lB1);
        __syncthreads();

        f16x8 af[4], bf[4];
#pragma unroll
        for (int mi = 0; mi < 4; ++mi) {
            int row = wr * 64 + mi * 16 + lr;
            af[mi] = *(const f16x8*)(As + row * 32 + (kg ^ ((row >> 1) & 3)) * 8);
        }
#pragma unroll
        for (int ni = 0; ni < 4; ++ni) {
            int rowb = wc * 64 + ni * 16 + lr;
            bf[ni] = *(const f16x8*)(Bs + rowb * 32 + (kg ^ ((rowb >> 1) & 3)) * 8);
        }
#pragma unroll
        for (int mi = 0; mi < 4; ++mi)
#pragma unroll
            for (int ni = 0; ni < 4; ++ni)
                acc[mi][ni] = __builtin_amdgcn_mfma_f32_16x16x32_f16(af[mi], bf[ni],
                                                                     acc[mi][ni], 0, 0, 0);
        __syncthreads();
    }

#pragma unroll
    for (int mi = 0; mi < 4; ++mi)
#pragma unroll
        for (int ni = 0; ni < 4; ++ni) {
            int col = colBase + wc * 64 + ni * 16 + lr;
            float bv = bias[col];
#pragma unroll
            for (int j = 0; j < 4; ++j) {
                int row = rowBase + wr * 64 + mi * 16 + kg * 4 + j;
                xw16[(size_t)row * HB + col] = (f16)(acc[mi][ni][j] + bv);
            }
        }
}

// ---------- fallback (small ws): direct GEMM + per-step kernels ----------
__global__ __launch_bounds__(256) void k_gemm_xw_direct(const float* __restrict__ x,
                                                        const f16* __restrict__ W16T,
                                                        const float* __restrict__ bias,
                                                        f16* __restrict__ xw16) {
    int lane = threadIdx.x & 63;
    int w = threadIdx.x >> 6;
    int wr = w >> 1, wc = w & 1;
    int rowBase = blockIdx.y * 64 + wr * 32;
    int colBase = blockIdx.x * 64 + wc * 32;
    int lr = lane & 15;
    int kg = lane >> 4;

    f32x4 acc[2][2] = {};

    int r0 = rowBase + lr;
    int r1 = rowBase + 16 + lr;
    const float* xrow0 = x + ((size_t)(r0 & 63) * TT + (r0 >> 6)) * DD;
    const float* xrow1 = x + ((size_t)(r1 & 63) * TT + (r1 >> 6)) * DD;
    const f16* wrow0 = W16T + (size_t)(colBase + lr) * DD;
    const f16* wrow1 = W16T + (size_t)(colBase + 16 + lr) * DD;

    for (int kk = 0; kk < DD; kk += 32) {
        int k = kk + kg * 8;
        const float4* pa0 = reinterpret_cast<const float4*>(xrow0 + k);
        const float4* pa1 = reinterpret_cast<const float4*>(xrow1 + k);
        float4 a0l = pa0[0], a0h = pa0[1];
        float4 a1l = pa1[0], a1h = pa1[1];
        f16x8 a0 = {(f16)a0l.x, (f16)a0l.y, (f16)a0l.z, (f16)a0l.w,
                    (f16)a0h.x, (f16)a0h.y, (f16)a0h.z, (f16)a0h.w};
        f16x8 a1 = {(f16)a1l.x, (f16)a1l.y, (f16)a1l.z, (f16)a1l.w,
                    (f16)a1h.x, (f16)a1h.y, (f16)a1h.z, (f16)a1h.w};
        f16x8 b0 = *reinterpret_cast<const f16x8*>(wrow0 + k);
        f16x8 b1 = *reinterpret_cast<const f16x8*>(wrow1 + k);
        acc[0][0] = __builtin_amdgcn_mfma_f32_16x16x32_f16(a0, b0, acc[0][0], 0, 0, 0);
        acc[0][1] = __builtin_amdgcn_mfma_f32_16x16x32_f16(a0, b1, acc[0][1], 0, 0, 0);
        acc[1][0] = __builtin_amdgcn_mfma_f32_16x16x32_f16(a1, b0, acc[1][0], 0, 0, 0);
        acc[1][1] = __builtin_amdgcn_mfma_f32_16x16x32_f16(a1, b1, acc[1][1], 0, 0, 0);
    }

#pragma unroll
    for (int mi = 0; mi < 2; ++mi)
#pragma unroll
        for (int ni = 0; ni < 2; ++ni) {
            int col = colBase + ni * 16 + lr;
            float bv = bias[col];
#pragma unroll
            for (int j = 0; j < 4; ++j) {
                int row = rowBase + mi * 16 + kg * 4 + j;
                xw16[(size_t)row * HB + col] = (f16)(acc[mi][ni][j] + bv);
            }
        }
}

__global__ __launch_bounds__(128) void k_rnn_step(const f16* __restrict__ hin,
                                                  const f16* __restrict__ WhT,
                                                  const f16* __restrict__ xw_t,
                                                  f16* __restrict__ hout,
                                                  float* __restrict__ dout, int last,
                                                  int first) {
    int lane = threadIdx.x & 63;
    int w = threadIdx.x >> 6;
    int m0 = blockIdx.y * 32 + w * 16;
    int n0 = blockIdx.x * 16;
    int lr = lane & 15;
    int kg = lane >> 4;

    f32x4 acc = {};
    if (!first) {
        const f16* arow = hin + (size_t)(m0 + lr) * HB;
        const f16* brow = WhT + (size_t)(n0 + lr) * HB;
#pragma unroll 4
        for (int kk = 0; kk < HB; kk += 32) {
            int k = kk + kg * 8;
            f16x8 a = *reinterpret_cast<const f16x8*>(arow + k);
            f16x8 b = *reinterpret_cast<const f16x8*>(brow + k);
            acc = __builtin_amdgcn_mfma_f32_16x16x32_f16(a, b, acc, 0, 0, 0);
        }
    }

#pragma unroll
    for (int j = 0; j < 4; ++j) {
        int row = m0 + kg * 4 + j;
        int col = n0 + lr;
        float pre = acc[j] + (float)xw_t[(size_t)row * HB + col];
        float h = tanhf(pre);
        hout[(size_t)row * HB + col] = (f16)h;
        if (last) dout[(size_t)row * HB + col] = h;
    }
}

// ---------- phase 2: batch-split persistent recurrence, per-row two-stage flags ----
// Group g=blockIdx&7 owns rows [g*8,g*8+8); 32 WGs per group, 64 cols each.
// R14's two-stage protocol at per-ROW granularity:
//  - ALL 8 waves finish in parallel: wave w -> row w, 1 col/lane (1 tanh, 2B store)
//  - per-wave two-stage publish: plain store -> vmcnt0 (L2 ack) -> plain flag ->
//    sc1 store -> vmcnt0 (L3 ack) -> sc1 flag. Flag idx = producerWG*8 + row.
//  - consumer wave polls its 4 producers x 8 rows with 32 lanes (sc0 fast path,
//    sc1 escalation after 8 tries = stale-L2-line escape; placement-independent)
//  - split-half MFMA pipeline: VMCNT(4) -> MFMA hv[0..3] while hv[4..7] in flight
//  - double-buffered reduce LDS -> one syncthreads/step
__global__ __launch_bounds__(512, 2) void k_rnn_persist(const f16* __restrict__ Wh16T,
                                                        const f16* __restrict__ xw16,
                                                        f16* __restrict__ hseq,
                                                        float* __restrict__ dout,
                                                        u32* __restrict__ bar) {
    __shared__ float red[2][8][8][68];  // [parity][wave][row][col+pad], 34KB
    int tid = threadIdx.x;
    int lane = tid & 63, w = tid >> 6;
    int lr = lane & 15, kg = lane >> 4;
    int g = blockIdx.x & 7;
    int j = blockIdx.x >> 3;
    int row0 = g * 8;
    int n0 = j * 64;

    f16x8 bfrag[4][8];
#pragma unroll
    for (int n = 0; n < 4; ++n) {
        const f16* brow = Wh16T + (size_t)(n0 + n * 16 + lr) * DD + w * 256 + kg * 8;
#pragma unroll
        for (int s = 0; s < 8; ++s) bfrag[n][s] = *(const f16x8*)(brow + s * 32);
    }

    // consumer flags: lane<32 polls producer WG j' = 4w + p (p=lane>>3), row r=lane&7
    int p_ = (lane >> 3) & 3;
    const u32* myflag =
        bar + (size_t)((((u32)(4 * w + p_) * 8 + g) * 8) + (lane & 7)) * 16;
    // producer flag for wave w (= row w): bid*8 + w
    u32* ourflag = bar + (size_t)((u32)blockIdx.x * 8 + w) * 16;

    for (int t = 0; t < TT; ++t) {
        // xw for finish output (row=w, col=lane); drained by poll vmcnt0s or compiler
        f16 xwv = xw16[((size_t)t * BB + row0 + w) * HB + n0 + lane];

        f32x4 acc[4] = {};
        if (t > 0) {
            // wait on my 4 producers x 8 rows (32 flags, sc0 -> sc1 after 8 tries)
            u32 tgt = (u32)t;
            u32 v = (lane < 32) ? ld_flag_sc0(myflag) : tgt;
            int tries = 0;
            while (!__all(v >= tgt)) {
                __builtin_amdgcn_s_sleep(1);
                if (lane < 32)
                    v = (++tries < 8) ? ld_flag_sc0(myflag) : ld_flag_sc1(myflag);
            }
            __builtin_amdgcn_sched_barrier(0);

            const f16* abase = hseq + ((size_t)(t - 1) * BB + row0 + (lr & 7)) * HB +
                               w * 256 + kg * 8;
            f16x8 hv[8];
            LOADM_SC0(hv, abase);
            VMCNT4;  // hv[0..3] landed
            __builtin_amdgcn_sched_barrier(0);
            if (lr >= 8) {
#pragma unroll
                for (int s = 0; s < 4; ++s) hv[s] = (f16x8)(f16)0;
            }
#pragma unroll
            for (int s = 0; s < 4; ++s)
#pragma unroll
                for (int n = 0; n < 4; ++n)
                    acc[n] = __builtin_amdgcn_mfma_f32_16x16x32_f16(hv[s], bfrag[n][s],
                                                                    acc[n], 0, 0, 0);
            VMCNT0;  // hv[4..7] landed
            __builtin_amdgcn_sched_barrier(0);
            if (lr >= 8) {
#pragma unroll
                for (int s = 4; s < 8; ++s) hv[s] = (f16x8)(f16)0;
            }
#pragma unroll
            for (int s = 4; s < 8; ++s)
#pragma unroll
                for (int n = 0; n < 4; ++n)
                    acc[n] = __builtin_amdgcn_mfma_f32_16x16x32_f16(hv[s], bfrag[n][s],
                                                                    acc[n], 0, 0, 0);
        }

        // partials -> red[t&1] (kg<2 lanes hold valid rows 0..7)
        if (kg < 2) {
#pragma unroll
            for (int n = 0; n < 4; ++n)
#pragma unroll
                for (int jj = 0; jj < 4; ++jj)
                    red[t & 1][w][kg * 4 + jj][n * 16 + lr] = acc[n][jj];
        }
        __syncthreads();  // the only barrier per step

        // finish: ALL waves — wave w owns row w, lane owns one col
        {
            float sum = 0.f;
#pragma unroll
            for (int ww = 0; ww < 8; ++ww) sum += red[t & 1][ww][w][lane];
            float h = tanhf(sum + (float)xwv);

            if (t == TT - 1) {
                dout[(size_t)(row0 + w) * HB + n0 + lane] = h;
            } else {
                union { f16 f; u16 s; } hb;
                hb.f = (f16)h;
                f16* dst = hseq + ((size_t)t * BB + row0 + w) * HB + n0 + lane;
                // stage 1: fast publish (same-XCD path)
                *(volatile u16*)dst = hb.s;  // plain: dirty in local L2
                VMCNT0;                      // L2 ack (wave-level)
                if (lane == 0)
                    *(volatile u32*)ourflag = (u32)(t + 1);  // fast flag
                // stage 2: safe publish (cross-XCD path)
                st_u16_sc1(dst, hb.s);  // sc1 payload -> L3
                VMCNT0;                 // L3 ack
                if (lane == 0)
                    __hip_atomic_store(ourflag, (u32)(t + 1), __ATOMIC_RELAXED,
                                       __HIP_MEMORY_SCOPE_AGENT);  // safe flag
            }
        }
        // no bottom barrier: waves run ahead to next step's poll + load
    }
}

extern "C" void kernel_launch(void* const* d_in, const int* in_sizes, int n_in,
                              void* d_out, int out_size, void* d_ws, size_t ws_size,
                              hipStream_t stream) {
    const float* x = (const float*)d_in[0];
    const float* W = (const float*)d_in[1];
    const float* Wh = (const float*)d_in[2];
    const float* bias = (const float*)d_in[3];
    float* dout = (float*)d_out;

    char* ws = (char*)d_ws;
    const size_t SZ_WT = (size_t)HB * DD * 2;       // 8 MB
    const size_t SZ_H = (size_t)BB * HB * 2;        // 256 KB
    const size_t SZ_XW = (size_t)TT * BB * HB * 2;  // 64 MB
    const size_t SZ_BAR = 262144;                   // 256 WGs x 8 rows x 64B (+slack)
    const size_t OFF_W = 0;
    const size_t OFF_WH = OFF_W + SZ_WT;
    const size_t OFF_H01 = OFF_WH + SZ_WT;          // fallback ping-pong (2 bufs)
    const size_t OFF_BAR = OFF_H01 + 2 * SZ_H;
    const size_t OFF_XW = OFF_BAR + SZ_BAR;
    const size_t OFF_HSEQ = OFF_XW + SZ_XW;         // doubles as x16 staging
    const size_t NEED_FULL = OFF_HSEQ + SZ_XW;      // ~145 MB

    f16* W16T = (f16*)(ws + OFF_W);
    f16* Wh16T = (f16*)(ws + OFF_WH);
    f16* h0 = (f16*)(ws + OFF_H01);
    f16* h1 = (f16*)(ws + OFF_H01 + SZ_H);
    u32* bar = (u32*)(ws + OFF_BAR);
    f16* xw16 = (f16*)(ws + OFF_XW);
    f16* hseq = (f16*)(ws + OFF_HSEQ);

    dim3 tgrid(32, 32);
    k_transpose_cvt<<<tgrid, 256, 0, stream>>>(W, W16T);
    k_transpose_cvt<<<tgrid, 256, 0, stream>>>(Wh, Wh16T);

    if (ws_size >= NEED_FULL) {
        f16* x16 = hseq;  // staging area, fully consumed by GEMM before persist
        k_cvt_x<<<TT * BB, 256, 0, stream>>>(x, x16);
        k_gemm_xw_lds<<<dim3(HB / 128, TT * BB / 128), 256, 0, stream>>>(x16, W16T, bias, xw16);
        hipMemsetAsync(bar, 0, SZ_BAR, stream);
        k_rnn_persist<<<256, 512, 0, stream>>>(Wh16T, xw16, hseq, dout, bar);
    } else {
        k_gemm_xw_direct<<<dim3(HB / 64, TT * BB / 64), 256, 0, stream>>>(x, W16T, bias, xw16);
        f16* hb[2] = {h0, h1};
        for (int t = 0; t < TT; ++t) {
            const f16* xwt = xw16 + (size_t)t * BB * HB;
            k_rnn_step<<<dim3(128, 2), 128, 0, stream>>>(hb[t & 1], Wh16T, xwt,
                                                         hb[(t + 1) & 1], dout,
                                                         t == TT - 1, t == 0);
        }
    }
}

// Round 16
// 1461.164 us; speedup vs baseline: 1.2145x; 1.2145x over previous
//
#include <hip/hip_runtime.h>
#include <hip/hip_bf16.h>
#include <hip/hip_fp16.h>

typedef _Float16 f16;
typedef _Float16 f16x8 __attribute__((ext_vector_type(8)));
typedef float f32x4 __attribute__((ext_vector_type(4)));
typedef unsigned int u32;
typedef unsigned long long u64;

#define HB 2048
#define DD 2048
#define TT 256
#define BB 64

typedef const __attribute__((address_space(1))) u32 gu32;
typedef __attribute__((address_space(3))) u32 lu32;

__device__ __forceinline__ void gl_lds16(const void* g, void* l) {
    __builtin_amdgcn_global_load_lds((gu32*)g, (lu32*)l, 16, 0, 0);
}

// 8x global_load_dwordx4, sc0: L1-bypass, served by L2 (dirty same-XCD) or L3 refill
#define LOADM_SC0(dst, ar)                                                    \
    asm volatile("global_load_dwordx4 %0, %8, off sc0\n\t"                    \
                 "global_load_dwordx4 %1, %8, off offset:64 sc0\n\t"          \
                 "global_load_dwordx4 %2, %8, off offset:128 sc0\n\t"         \
                 "global_load_dwordx4 %3, %8, off offset:192 sc0\n\t"         \
                 "global_load_dwordx4 %4, %8, off offset:256 sc0\n\t"         \
                 "global_load_dwordx4 %5, %8, off offset:320 sc0\n\t"         \
                 "global_load_dwordx4 %6, %8, off offset:384 sc0\n\t"         \
                 "global_load_dwordx4 %7, %8, off offset:448 sc0"             \
                 : "=&v"(dst[0]), "=&v"(dst[1]), "=&v"(dst[2]), "=&v"(dst[3]),\
                   "=&v"(dst[4]), "=&v"(dst[5]), "=&v"(dst[6]), "=&v"(dst[7]) \
                 : "v"(ar)                                                    \
                 : "memory")

#define VMCNT0 asm volatile("s_waitcnt vmcnt(0)" ::: "memory")
#define VMCNT4 asm volatile("s_waitcnt vmcnt(4)" ::: "memory")

__device__ __forceinline__ u32 ld_flag_sc0(const u32* p) {
    u32 v;
    asm volatile("global_load_dword %0, %1, off sc0\n\ts_waitcnt vmcnt(0)"
                 : "=v"(v) : "v"(p) : "memory");
    return v;
}
__device__ __forceinline__ u32 ld_flag_sc1(const u32* p) {
    u32 v;
    asm volatile("global_load_dword %0, %1, off sc1\n\ts_waitcnt vmcnt(0)"
                 : "=v"(v) : "v"(p) : "memory");
    return v;
}

// ---------- transpose + convert fp32 [R][C] -> fp16 [C][R] (square 2048) ----------
__global__ __launch_bounds__(256) void k_transpose_cvt(const float* __restrict__ src,
                                                       f16* __restrict__ dst) {
    __shared__ f16 tile[64][65];
    int bx = blockIdx.x * 64;
    int by = blockIdx.y * 64;
    int tx = threadIdx.x & 63;
    int ty = threadIdx.x >> 6;
#pragma unroll
    for (int r = ty; r < 64; r += 4)
        tile[r][tx] = (f16)src[(size_t)(by + r) * HB + bx + tx];
    __syncthreads();
#pragma unroll
    for (int r = ty; r < 64; r += 4)
        dst[(size_t)(bx + r) * HB + by + tx] = tile[tx][r];
}

// ---------- convert/gather x [b][t][d] fp32 -> a16 [t*64+b][d] fp16 ----------
__global__ __launch_bounds__(256) void k_cvt_x(const float* __restrict__ x,
                                               f16* __restrict__ a16) {
    int r = blockIdx.x;  // r = t*64+b
    int d = threadIdx.x * 8;
    const float* src = x + ((size_t)(r & 63) * TT + (r >> 6)) * DD + d;
    float4 v0 = *(const float4*)src;
    float4 v1 = *(const float4*)(src + 4);
    f16x8 o = {(f16)v0.x, (f16)v0.y, (f16)v0.z, (f16)v0.w,
               (f16)v1.x, (f16)v1.y, (f16)v1.z, (f16)v1.w};
    *(f16x8*)(a16 + (size_t)r * DD + d) = o;
}

// ---------- phase 1: 128x128x32 LDS-staged MFMA GEMM, xw16 = a16 @ W + b ----------
__global__ __launch_bounds__(256) void k_gemm_xw_lds(const f16* __restrict__ a16,
                                                     const f16* __restrict__ W16T,
                                                     const float* __restrict__ bias,
                                                     f16* __restrict__ xw16) {
    __shared__ f16 As[128 * 32];
    __shared__ f16 Bs[128 * 32];
    int tid = threadIdx.x;
    int lane = tid & 63, w = tid >> 6;
    int wr = w >> 1, wc = w & 1;
    int lr = lane & 15, kg = lane >> 4;
    int rowBase = blockIdx.y * 128;
    int colBase = blockIdx.x * 128;

    f32x4 acc[4][4] = {};

    int r0 = tid >> 2, c0 = ((tid & 3) ^ ((r0 >> 1) & 3)) * 8;
    int u1 = tid + 256;
    int r1 = u1 >> 2, c1 = ((u1 & 3) ^ ((r1 >> 1) & 3)) * 8;
    const f16* gA0 = a16 + (size_t)(rowBase + r0) * DD + c0;
    const f16* gA1 = a16 + (size_t)(rowBase + r1) * DD + c1;
    const f16* gB0 = W16T + (size_t)(colBase + r0) * DD + c0;
    const f16* gB1 = W16T + (size_t)(colBase + r1) * DD + c1;
    f16* lA0 = As + (size_t)(w * 64) * 8;
    f16* lA1 = As + (size_t)(256 + w * 64) * 8;
    f16* lB0 = Bs + (size_t)(w * 64) * 8;
    f16* lB1 = Bs + (size_t)(256 + w * 64) * 8;

    for (int kk = 0; kk < DD; kk += 32) {
        gl_lds16(gA0 + kk, lA0);
        gl_lds16(gA1 + kk, lA1);
        gl_lds16(gB0 + kk, lB0);
        gl_lds16(gB1 + kk, lB1);
        __syncthreads();

        f16x8 af[4], bf[4];
#pragma unroll
        for (int mi = 0; mi < 4; ++mi) {
            int row = wr * 64 + mi * 16 + lr;
            af[mi] = *(const f16x8*)(As + row * 32 + (kg ^ ((row >> 1) & 3)) * 8);
        }
#pragma unroll
        for (int ni = 0; ni < 4; ++ni) {
            int rowb = wc * 64 + ni * 16 + lr;
            bf[ni] = *(const f16x8*)(Bs + rowb * 32 + (kg ^ ((rowb >> 1) & 3)) * 8);
        }
#pragma unroll
        for (int mi = 0; mi < 4; ++mi)
#pragma unroll
            for (int ni = 0; ni < 4; ++ni)
                acc[mi][ni] = __builtin_amdgcn_mfma_f32_16x16x32_f16(af[mi], bf[ni],
                                                                     acc[mi][ni], 0, 0, 0);
        __syncthreads();
    }

#pragma unroll
    for (int mi = 0; mi < 4; ++mi)
#pragma unroll
        for (int ni = 0; ni < 4; ++ni) {
            int col = colBase + wc * 64 + ni * 16 + lr;
            float bv = bias[col];
#pragma unroll
            for (int j = 0; j < 4; ++j) {
                int row = rowBase + wr * 64 + mi * 16 + kg * 4 + j;
                xw16[(size_t)row * HB + col] = (f16)(acc[mi][ni][j] + bv);
            }
        }
}

// ---------- fallback (small ws): direct GEMM + per-step kernels ----------
__global__ __launch_bounds__(256) void k_gemm_xw_direct(const float* __restrict__ x,
                                                        const f16* __restrict__ W16T,
                                                        const float* __restrict__ bias,
                                                        f16* __restrict__ xw16) {
    int lane = threadIdx.x & 63;
    int w = threadIdx.x >> 6;
    int wr = w >> 1, wc = w & 1;
    int rowBase = blockIdx.y * 64 + wr * 32;
    int colBase = blockIdx.x * 64 + wc * 32;
    int lr = lane & 15;
    int kg = lane >> 4;

    f32x4 acc[2][2] = {};

    int r0 = rowBase + lr;
    int r1 = rowBase + 16 + lr;
    const float* xrow0 = x + ((size_t)(r0 & 63) * TT + (r0 >> 6)) * DD;
    const float* xrow1 = x + ((size_t)(r1 & 63) * TT + (r1 >> 6)) * DD;
    const f16* wrow0 = W16T + (size_t)(colBase + lr) * DD;
    const f16* wrow1 = W16T + (size_t)(colBase + 16 + lr) * DD;

    for (int kk = 0; kk < DD; kk += 32) {
        int k = kk + kg * 8;
        const float4* pa0 = reinterpret_cast<const float4*>(xrow0 + k);
        const float4* pa1 = reinterpret_cast<const float4*>(xrow1 + k);
        float4 a0l = pa0[0], a0h = pa0[1];
        float4 a1l = pa1[0], a1h = pa1[1];
        f16x8 a0 = {(f16)a0l.x, (f16)a0l.y, (f16)a0l.z, (f16)a0l.w,
                    (f16)a0h.x, (f16)a0h.y, (f16)a0h.z, (f16)a0h.w};
        f16x8 a1 = {(f16)a1l.x, (f16)a1l.y, (f16)a1l.z, (f16)a1l.w,
                    (f16)a1h.x, (f16)a1h.y, (f16)a1h.z, (f16)a1h.w};
        f16x8 b0 = *reinterpret_cast<const f16x8*>(wrow0 + k);
        f16x8 b1 = *reinterpret_cast<const f16x8*>(wrow1 + k);
        acc[0][0] = __builtin_amdgcn_mfma_f32_16x16x32_f16(a0, b0, acc[0][0], 0, 0, 0);
        acc[0][1] = __builtin_amdgcn_mfma_f32_16x16x32_f16(a0, b1, acc[0][1], 0, 0, 0);
        acc[1][0] = __builtin_amdgcn_mfma_f32_16x16x32_f16(a1, b0, acc[1][0], 0, 0, 0);
        acc[1][1] = __builtin_amdgcn_mfma_f32_16x16x32_f16(a1, b1, acc[1][1], 0, 0, 0);
    }

#pragma unroll
    for (int mi = 0; mi < 2; ++mi)
#pragma unroll
        for (int ni = 0; ni < 2; ++ni) {
            int col = colBase + ni * 16 + lr;
            float bv = bias[col];
#pragma unroll
            for (int j = 0; j < 4; ++j) {
                int row = rowBase + mi * 16 + kg * 4 + j;
                xw16[(size_t)row * HB + col] = (f16)(acc[mi][ni][j] + bv);
            }
        }
}

__global__ __launch_bounds__(128) void k_rnn_step(const f16* __restrict__ hin,
                                                  const f16* __restrict__ WhT,
                                                  const f16* __restrict__ xw_t,
                                                  f16* __restrict__ hout,
                                                  float* __restrict__ dout, int last,
                                                  int first) {
    int lane = threadIdx.x & 63;
    int w = threadIdx.x >> 6;
    int m0 = blockIdx.y * 32 + w * 16;
    int n0 = blockIdx.x * 16;
    int lr = lane & 15;
    int kg = lane >> 4;

    f32x4 acc = {};
    if (!first) {
        const f16* arow = hin + (size_t)(m0 + lr) * HB;
        const f16* brow = WhT + (size_t)(n0 + lr) * HB;
#pragma unroll 4
        for (int kk = 0; kk < HB; kk += 32) {
            int k = kk + kg * 8;
            f16x8 a = *reinterpret_cast<const f16x8*>(arow + k);
            f16x8 b = *reinterpret_cast<const f16x8*>(brow + k);
            acc = __builtin_amdgcn_mfma_f32_16x16x32_f16(a, b, acc, 0, 0, 0);
        }
    }

#pragma unroll
    for (int j = 0; j < 4; ++j) {
        int row = m0 + kg * 4 + j;
        int col = n0 + lr;
        float pre = acc[j] + (float)xw_t[(size_t)row * HB + col];
        float h = tanhf(pre);
        hout[(size_t)row * HB + col] = (f16)h;
        if (last) dout[(size_t)row * HB + col] = h;
    }
}

// ---------- phase 2: batch-split persistent recurrence, two-stage flag publish ----
// R14's proven protocol (best so far: 1283us persist), plus split-half MFMA
// pipeline (VMCNT(4) -> compute hv[0..3] while hv[4..7] in flight).
// Group g=blockIdx&7 owns rows [g*8,g*8+8); 32 WGs per group, 64 cols each.
//  (a) TWO-STAGE flag on one address: plain payload -> vmcnt0 (L2 ack) -> plain
//      flag (same-XCD fast path) -> sc1 payload -> vmcnt0 (L3 ack) -> sc1 flag
//      (cross-XCD safe path). Placement-independent, deadlock-free.
//  (b) double-buffered reduce LDS -> ONE syncthreads/step; waves 2-7 overlap
//      next step's flag poll + payload load with finish-waves' store drain.
__global__ __launch_bounds__(512, 2) void k_rnn_persist(const f16* __restrict__ Wh16T,
                                                        const f16* __restrict__ xw16,
                                                        f16* __restrict__ hseq,
                                                        float* __restrict__ dout,
                                                        u32* __restrict__ bar) {
    __shared__ float red[2][8][8][68];  // [step parity][wave][row][col+pad], 34KB
    int tid = threadIdx.x;
    int lane = tid & 63, w = tid >> 6;
    int lr = lane & 15, kg = lane >> 4;
    int g = blockIdx.x & 7;
    int j = blockIdx.x >> 3;
    int row0 = g * 8;
    int n0 = j * 64;

    f16x8 bfrag[4][8];
#pragma unroll
    for (int n = 0; n < 4; ++n) {
        const f16* brow = Wh16T + (size_t)(n0 + n * 16 + lr) * DD + w * 256 + kg * 8;
#pragma unroll
        for (int s = 0; s < 8; ++s) bfrag[n][s] = *(const f16x8*)(brow + s * 32);
    }

    int f_row = tid >> 4;
    int f_c = (tid & 15) * 4;

    // consumer flags: lane<8 polls producer WG j' = 4w + (lane>>1), half = lane&1
    const u32* myflag =
        bar + (size_t)((((((w << 2) | (lane >> 1)) << 3) | g) << 1) | (lane & 1)) * 16;
    // producer flag for finish wave w (0/1): (bid<<1)|w
    u32* ourflag = bar + (size_t)(((u32)blockIdx.x << 1) | (w & 1)) * 16;

    for (int t = 0; t < TT; ++t) {
        u64 xwv = 0;
        if (tid < 128)
            xwv = *(const u64*)(xw16 + ((size_t)t * BB + row0 + f_row) * HB + n0 + f_c);

        f32x4 acc[4] = {};
        if (t > 0) {
            // wait on my 8 producer-half flags (sc0 fast path, sc1 after 8 tries)
            u32 tgt = (u32)t;
            u32 v = (lane < 8) ? ld_flag_sc0(myflag) : tgt;
            int tries = 0;
            while (!__all(v >= tgt)) {
                __builtin_amdgcn_s_sleep(1);
                if (lane < 8)
                    v = (++tries < 8) ? ld_flag_sc0(myflag) : ld_flag_sc1(myflag);
            }
            __builtin_amdgcn_sched_barrier(0);

            const f16* abase = hseq + ((size_t)(t - 1) * BB + row0 + (lr & 7)) * HB +
                               w * 256 + kg * 8;
            f16x8 hv[8];
            LOADM_SC0(hv, abase);
            // split-half pipeline: compute hv[0..3] while hv[4..7] are in flight
            VMCNT4;
            __builtin_amdgcn_sched_barrier(0);
            if (lr >= 8) {
#pragma unroll
                for (int s = 0; s < 4; ++s) hv[s] = (f16x8)(f16)0;
            }
#pragma unroll
            for (int s = 0; s < 4; ++s)
#pragma unroll
                for (int n = 0; n < 4; ++n)
                    acc[n] = __builtin_amdgcn_mfma_f32_16x16x32_f16(hv[s], bfrag[n][s],
                                                                    acc[n], 0, 0, 0);
            VMCNT0;
            __builtin_amdgcn_sched_barrier(0);
            if (lr >= 8) {
#pragma unroll
                for (int s = 4; s < 8; ++s) hv[s] = (f16x8)(f16)0;
            }
#pragma unroll
            for (int s = 4; s < 8; ++s)
#pragma unroll
                for (int n = 0; n < 4; ++n)
                    acc[n] = __builtin_amdgcn_mfma_f32_16x16x32_f16(hv[s], bfrag[n][s],
                                                                    acc[n], 0, 0, 0);
        }

        // partials -> red[t&1] (kg<2 lanes hold valid rows 0..7)
        if (kg < 2) {
#pragma unroll
            for (int n = 0; n < 4; ++n)
#pragma unroll
                for (int jj = 0; jj < 4; ++jj)
                    red[t & 1][w][kg * 4 + jj][n * 16 + lr] = acc[n][jj];
        }
        __syncthreads();  // the ONLY barrier per step (double-buffered red)

        if (tid < 128) {
            float4 sum = {0.f, 0.f, 0.f, 0.f};
#pragma unroll
            for (int ww = 0; ww < 8; ++ww) {
                float4 v = *(const float4*)&red[t & 1][ww][f_row][f_c];
                sum.x += v.x; sum.y += v.y; sum.z += v.z; sum.w += v.w;
            }
            union { u64 q; f16 h[4]; } xwu;
            xwu.q = xwv;
            float h0 = tanhf(sum.x + (float)xwu.h[0]);
            float h1 = tanhf(sum.y + (float)xwu.h[1]);
            float h2 = tanhf(sum.z + (float)xwu.h[2]);
            float h3 = tanhf(sum.w + (float)xwu.h[3]);

            if (t == TT - 1) {
                float4 o = {h0, h1, h2, h3};
                *(float4*)(dout + (size_t)(row0 + f_row) * HB + n0 + f_c) = o;
            } else {
                union { u64 q; f16 h[4]; } ho;
                ho.h[0] = (f16)h0; ho.h[1] = (f16)h1;
                ho.h[2] = (f16)h2; ho.h[3] = (f16)h3;
                u64* dst = (u64*)(hseq + ((size_t)t * BB + row0 + f_row) * HB + n0 + f_c);
                // stage 1: fast publish (same-XCD path)
                *(volatile u64*)dst = ho.q;            // plain: dirty in local L2
                VMCNT0;                                // L2 ack only (fast)
                if ((tid & 63) == 0)
                    *(volatile u32*)ourflag = (u32)(t + 1);  // fast flag (local L2)
                // stage 2: safe publish (cross-XCD path)
                __hip_atomic_store(dst, ho.q, __ATOMIC_RELAXED,
                                   __HIP_MEMORY_SCOPE_AGENT);  // sc1 payload -> L3
                VMCNT0;                                        // L3 ack
                if ((tid & 63) == 0)
                    __hip_atomic_store(ourflag, (u32)(t + 1), __ATOMIC_RELAXED,
                                       __HIP_MEMORY_SCOPE_AGENT);  // safe flag (L3)
            }
        }
        // no bottom barrier: waves 2-7 run ahead to next step's poll + load
    }
}

extern "C" void kernel_launch(void* const* d_in, const int* in_sizes, int n_in,
                              void* d_out, int out_size, void* d_ws, size_t ws_size,
                              hipStream_t stream) {
    const float* x = (const float*)d_in[0];
    const float* W = (const float*)d_in[1];
    const float* Wh = (const float*)d_in[2];
    const float* bias = (const float*)d_in[3];
    float* dout = (float*)d_out;

    char* ws = (char*)d_ws;
    const size_t SZ_WT = (size_t)HB * DD * 2;       // 8 MB
    const size_t SZ_H = (size_t)BB * HB * 2;        // 256 KB
    const size_t SZ_XW = (size_t)TT * BB * HB * 2;  // 64 MB
    const size_t OFF_W = 0;
    const size_t OFF_WH = OFF_W + SZ_WT;
    const size_t OFF_H01 = OFF_WH + SZ_WT;          // fallback ping-pong (2 bufs)
    const size_t OFF_BAR = OFF_H01 + 2 * SZ_H;
    const size_t OFF_XW = OFF_BAR + 65536;
    const size_t OFF_HSEQ = OFF_XW + SZ_XW;         // doubles as x16 staging
    const size_t NEED_FULL = OFF_HSEQ + SZ_XW;      // ~145 MB

    f16* W16T = (f16*)(ws + OFF_W);
    f16* Wh16T = (f16*)(ws + OFF_WH);
    f16* h0 = (f16*)(ws + OFF_H01);
    f16* h1 = (f16*)(ws + OFF_H01 + SZ_H);
    u32* bar = (u32*)(ws + OFF_BAR);
    f16* xw16 = (f16*)(ws + OFF_XW);
    f16* hseq = (f16*)(ws + OFF_HSEQ);

    dim3 tgrid(32, 32);
    k_transpose_cvt<<<tgrid, 256, 0, stream>>>(W, W16T);
    k_transpose_cvt<<<tgrid, 256, 0, stream>>>(Wh, Wh16T);

    if (ws_size >= NEED_FULL) {
        f16* x16 = hseq;  // staging area, fully consumed by GEMM before persist
        k_cvt_x<<<TT * BB, 256, 0, stream>>>(x, x16);
        k_gemm_xw_lds<<<dim3(HB / 128, TT * BB / 128), 256, 0, stream>>>(x16, W16T, bias, xw16);
        hipMemsetAsync(bar, 0, 65536, stream);
        k_rnn_persist<<<256, 512, 0, stream>>>(Wh16T, xw16, hseq, dout, bar);
    } else {
        k_gemm_xw_direct<<<dim3(HB / 64, TT * BB / 64), 256, 0, stream>>>(x, W16T, bias, xw16);
        f16* hb[2] = {h0, h1};
        for (int t = 0; t < TT; ++t) {
            const f16* xwt = xw16 + (size_t)t * BB * HB;
            k_rnn_step<<<dim3(128, 2), 128, 0, stream>>>(hb[t & 1], Wh16T, xwt,
                                                         hb[(t + 1) & 1], dout,
                                                         t == TT - 1, t == 0);
        }
    }
}